// Round 6
// baseline (639.943 us; speedup 1.0000x reference)
//
#include <hip/hip_runtime.h>
#include <hip/hip_bf16.h>

#define N_NODES 100000
#define N_EDGES 1600000
#define IN_DIM 128
#define HID 64

// ---------------- threefry2x32, key = (0, 42)  (jax.random.key(42)) ----------------
__device__ __forceinline__ unsigned rotl32(unsigned x, unsigned r) {
    return (x << r) | (x >> (32u - r));
}

__device__ __forceinline__ void threefry2x32_k42(unsigned x0, unsigned x1,
                                                 unsigned& o0, unsigned& o1) {
    const unsigned ks0 = 0u;
    const unsigned ks1 = 42u;
    const unsigned ks2 = 0u ^ 42u ^ 0x1BD11BDAu;
    x0 += ks0; x1 += ks1;
    x0 += x1; x1 = rotl32(x1, 13); x1 ^= x0;
    x0 += x1; x1 = rotl32(x1, 15); x1 ^= x0;
    x0 += x1; x1 = rotl32(x1, 26); x1 ^= x0;
    x0 += x1; x1 = rotl32(x1, 6);  x1 ^= x0;
    x0 += ks1; x1 += ks2 + 1u;
    x0 += x1; x1 = rotl32(x1, 17); x1 ^= x0;
    x0 += x1; x1 = rotl32(x1, 29); x1 ^= x0;
    x0 += x1; x1 = rotl32(x1, 16); x1 ^= x0;
    x0 += x1; x1 = rotl32(x1, 24); x1 ^= x0;
    x0 += ks2; x1 += ks0 + 2u;
    x0 += x1; x1 = rotl32(x1, 13); x1 ^= x0;
    x0 += x1; x1 = rotl32(x1, 15); x1 ^= x0;
    x0 += x1; x1 = rotl32(x1, 26); x1 ^= x0;
    x0 += x1; x1 = rotl32(x1, 6);  x1 ^= x0;
    x0 += ks0; x1 += ks1 + 3u;
    x0 += x1; x1 = rotl32(x1, 17); x1 ^= x0;
    x0 += x1; x1 = rotl32(x1, 29); x1 ^= x0;
    x0 += x1; x1 = rotl32(x1, 16); x1 ^= x0;
    x0 += x1; x1 = rotl32(x1, 24); x1 ^= x0;
    x0 += ks1; x1 += ks2 + 4u;
    x0 += x1; x1 = rotl32(x1, 13); x1 ^= x0;
    x0 += x1; x1 = rotl32(x1, 15); x1 ^= x0;
    x0 += x1; x1 = rotl32(x1, 26); x1 ^= x0;
    x0 += x1; x1 = rotl32(x1, 6);  x1 ^= x0;
    x0 += ks2; x1 += ks0 + 5u;
    o0 = x0; o1 = x1;
}

// ---------------- edge-index dtype detection (int64 vs int32) ----------------
__global__ void k_detect(const unsigned* __restrict__ ei_words, int* __restrict__ flag) {
    __shared__ unsigned red[256];
    int t = threadIdx.x;
    unsigned acc = 0;
    for (int i = t; i < 4096; i += 256) acc |= ei_words[2 * i + 1];
    red[t] = acc;
    __syncthreads();
    for (int s = 128; s; s >>= 1) {
        if (t < s) red[t] |= red[t + s];
        __syncthreads();
    }
    if (t == 0) *flag = (red[0] == 0u) ? 1 : 0;  // 1 => int64
}

__device__ __forceinline__ int edge_at(const int* __restrict__ e32,
                                       const long long* __restrict__ e64,
                                       int is64, int j) {
    return is64 ? (int)e64[j] : e32[j];
}

// ---------------- K0: h = x @ W_conv  [100000,128]x[128,64] -> fp32 ----------------
__global__ __launch_bounds__(256) void k_gemm(const float* __restrict__ x,
                                              const float* __restrict__ W,
                                              float* __restrict__ h) {
    __shared__ float Wl[IN_DIM * HID];  // 32 KB
    __shared__ float xs[16][IN_DIM];    // 8 KB
    const int t = threadIdx.x;
    const float4* W4 = (const float4*)W;
    for (int i = t; i < IN_DIM * HID / 4; i += 256) ((float4*)Wl)[i] = W4[i];
    const int base = blockIdx.x * 16;
    const float4* x4 = (const float4*)(x + (size_t)base * IN_DIM);
    for (int i = t; i < 16 * IN_DIM / 4; i += 256) ((float4*)xs)[i] = x4[i];
    __syncthreads();
    const int d = t & 63, g = t >> 6;
    float a0 = 0.f, a1 = 0.f, a2 = 0.f, a3 = 0.f;
#pragma unroll 4
    for (int k = 0; k < IN_DIM; k++) {
        float w = Wl[k * HID + d];
        a0 += xs[g][k] * w;
        a1 += xs[g + 4][k] * w;
        a2 += xs[g + 8][k] * w;
        a3 += xs[g + 12][k] * w;
    }
    h[(size_t)(base + g) * HID + d] = a0;
    h[(size_t)(base + g + 4) * HID + d] = a1;
    h[(size_t)(base + g + 8) * HID + d] = a2;
    h[(size_t)(base + g + 12) * HID + d] = a3;
}

// ---------------- degree (targets, incl. self-loop) ----------------
__global__ void k_deg_init(float* __restrict__ deg) {
    int i = blockIdx.x * 256 + threadIdx.x;
    if (i < N_NODES) deg[i] = 1.0f;  // self-loop
}

__global__ void k_deg_acc(const int* __restrict__ e32, const long long* __restrict__ e64,
                          const int* __restrict__ flag, float* __restrict__ deg) {
    int e = blockIdx.x * 256 + threadIdx.x;
    if (e < N_EDGES) {
        int c = edge_at(e32, e64, *flag, N_EDGES + e);
        atomicAdd(&deg[c], 1.0f);
    }
}

__global__ void k_dinv(float* __restrict__ deg) {
    int i = blockIdx.x * 256 + threadIdx.x;
    if (i < N_NODES) deg[i] = rsqrtf(deg[i]);  // deg >= 1 always
}

// ---------------- agg init with self-loop contribution ----------------
__global__ __launch_bounds__(256) void k_self(const float* __restrict__ h,
                                              const float* __restrict__ dinv,
                                              float* __restrict__ agg) {
    int i = blockIdx.x * 256 + threadIdx.x;
    int v = i >> 6;
    float di = dinv[v];
    agg[i] = h[i] * di * di;
}

// ---------------- edge scatter (1 wave per edge, lane = dim) ----------------
__global__ __launch_bounds__(256) void k_scatter(const int* __restrict__ e32,
                                                 const long long* __restrict__ e64,
                                                 const int* __restrict__ flag,
                                                 const float* __restrict__ dinv,
                                                 const float* __restrict__ h,
                                                 float* __restrict__ agg) {
    int e = blockIdx.x * 4 + (threadIdx.x >> 6);
    if (e >= N_EDGES) return;
    int lane = threadIdx.x & 63;
    int f = *flag;
    int r = edge_at(e32, e64, f, e);
    int c = edge_at(e32, e64, f, N_EDGES + e);
    float w = dinv[r] * dinv[c];
    atomicAdd(&agg[(size_t)c * HID + lane], h[(size_t)r * HID + lane] * w);
}

// ---------------- bias + relu + dropout(threefry, partitionable) + [64->2] matvec ----
__global__ __launch_bounds__(256) void k_out(const float* __restrict__ agg,
                                             const float* __restrict__ bconv,
                                             const float* __restrict__ Wlin,
                                             const float* __restrict__ blin,
                                             float* __restrict__ out) {
    int n = blockIdx.x * 4 + (threadIdx.x >> 6);
    int d = threadIdx.x & 63;
    float v = agg[(size_t)n * HID + d] + bconv[d];
    v = fmaxf(v, 0.f);
    // JAX threefry_partitionable, bit_width=32: counts = iota(uint64);
    // (bits1, bits2) = threefry2x32(key, (counts>>32, counts&0xffffffff)) = (0, i);
    // returned 32-bit stream = bits1 ^ bits2.  keep iff uniform<0.5 iff MSB==0.
    unsigned i = (unsigned)(n * HID + d);
    unsigned o0, o1;
    threefry2x32_k42(0u, i, o0, o1);
    unsigned bits = o0 ^ o1;
    v = (bits & 0x80000000u) ? 0.f : v * 2.f;  // /(1-p) with p=0.5
    float a0 = v * Wlin[d * 2 + 0];
    float a1 = v * Wlin[d * 2 + 1];
#pragma unroll
    for (int off = 32; off; off >>= 1) {
        a0 += __shfl_down(a0, off);
        a1 += __shfl_down(a1, off);
    }
    if (d == 0) {
        out[(size_t)n * 2 + 0] = a0 + blin[0];
        out[(size_t)n * 2 + 1] = a1 + blin[1];
    }
}

extern "C" void kernel_launch(void* const* d_in, const int* in_sizes, int n_in,
                              void* d_out, int out_size, void* d_ws, size_t ws_size,
                              hipStream_t stream) {
    // Map inputs BY ELEMENT COUNT (all unique) — robust to positional order.
    const float* x  = (const float*)d_in[0];
    const void*  ei = d_in[1];
    const float* Wc = (const float*)d_in[2];
    const float* bc = (const float*)d_in[3];
    const float* Wl = (const float*)d_in[4];
    const float* bl = (const float*)d_in[5];
    for (int i = 0; i < n_in; i++) {
        switch (in_sizes[i]) {
            case N_NODES * IN_DIM:   x  = (const float*)d_in[i]; break;  // 12800000
            case 2 * N_EDGES:                                            // 3200000
            case 4 * N_EDGES:        ei = d_in[i]; break;
            case IN_DIM * HID:       Wc = (const float*)d_in[i]; break;  // 8192
            case HID:                bc = (const float*)d_in[i]; break;  // 64
            case HID * 2:            Wl = (const float*)d_in[i]; break;  // 128
            case 2:                  bl = (const float*)d_in[i]; break;  // 2
            default: break;
        }
    }
    float* out = (float*)d_out;

    char* ws = (char*)d_ws;
    float* h    = (float*)ws;                                      // 25.6 MB
    float* agg  = (float*)(ws + (size_t)N_NODES * HID * 4);        // 25.6 MB
    float* deg  = (float*)(ws + (size_t)2 * N_NODES * HID * 4);    // 0.4 MB
    int*   flag = (int*)(ws + (size_t)2 * N_NODES * HID * 4 + (size_t)N_NODES * 4);

    const int*       e32 = (const int*)ei;
    const long long* e64 = (const long long*)ei;

    k_detect<<<1, 256, 0, stream>>>((const unsigned*)ei, flag);
    k_gemm<<<N_NODES / 16, 256, 0, stream>>>(x, Wc, h);
    k_deg_init<<<(N_NODES + 255) / 256, 256, 0, stream>>>(deg);
    k_deg_acc<<<(N_EDGES + 255) / 256, 256, 0, stream>>>(e32, e64, flag, deg);
    k_dinv<<<(N_NODES + 255) / 256, 256, 0, stream>>>(deg);
    k_self<<<N_NODES * HID / 256, 256, 0, stream>>>(h, deg, agg);
    k_scatter<<<N_EDGES / 4, 256, 0, stream>>>(e32, e64, flag, deg, h, agg);
    k_out<<<N_NODES / 4, 256, 0, stream>>>(agg, bc, Wl, bl, out);
}